// Round 1
// baseline (2228.395 us; speedup 1.0000x reference)
//
#include <hip/hip_runtime.h>
#include <hip/hip_bf16.h>

#define C 96
#define TN 64          // node rows per GEMM block
#define SX_LD 100      // padded LDS leading dim for X tile (breaks bank conflicts)

// ---------------------------------------------------------------------------
// Degree count: one thread per edge, atomicAdd 1.0 into deg[dst]
__global__ __launch_bounds__(256) void deg_kernel(const int* __restrict__ dst,
                                                  float* __restrict__ deg, int E) {
    int e = blockIdx.x * 256 + threadIdx.x;
    if (e < E) atomicAdd(&deg[dst[e]], 1.0f);
}

// deg[i] -> 1/max(deg,1)
__global__ __launch_bounds__(256) void inv_kernel(float* __restrict__ deg, int n) {
    int i = blockIdx.x * 256 + threadIdx.x;
    if (i < n) deg[i] = 1.0f / fmaxf(deg[i], 1.0f);
}

// ---------------------------------------------------------------------------
// Edge scatter: thread handles one (edge, float4-chunk). 24 chunks per edge.
__global__ __launch_bounds__(256) void scatter_kernel(const float* __restrict__ H,
                                                      const int* __restrict__ src,
                                                      const int* __restrict__ dst,
                                                      float* __restrict__ agg, int E) {
    int i = blockIdx.x * 256 + threadIdx.x;
    if (i >= E * 24) return;
    int e = i / 24;
    int q = i - e * 24;
    int s = src[e], d = dst[e];
    const float4 v = ((const float4*)(H + (long)s * C))[q];
    float* a = agg + (long)d * C + q * 4;
    atomicAdd(a + 0, v.x);
    atomicAdd(a + 1, v.y);
    atomicAdd(a + 2, v.z);
    atomicAdd(a + 3, v.w);
}

// ---------------------------------------------------------------------------
// GEMM Y[n][c] = sum_k X[n][k] * W[k][c], optionally fused epilogue:
//   Y = (RELU?)(AGG[n][c]*INV[n] + gemm + BIAS[c])
// Block: 256 threads, TN=64 rows. W (96x96) + X tile staged in LDS.
// Thread (tx=t&15, ty=t>>4) computes rows ty*4..+3, cols tx*6..+5 (4x6 acc).
template <bool FUSE, bool RELU>
__global__ __launch_bounds__(256) void gemm96_kernel(const float* __restrict__ X,
                                                     const float* __restrict__ W,
                                                     const float* __restrict__ AGG,
                                                     const float* __restrict__ INV,
                                                     const float* __restrict__ BIAS,
                                                     float* __restrict__ Y, int n) {
    __shared__ float sW[C * C];        // [k][c] row-major
    __shared__ float sX[TN * SX_LD];   // padded rows

    const int t = threadIdx.x;
    const int row0 = blockIdx.x * TN;

    // Load W (coalesced, 9216 floats)
    for (int i = t; i < C * C; i += 256) sW[i] = W[i];

    // Load X tile as float4 (24 float4 per row), guard tail rows
    for (int i = t; i < TN * 24; i += 256) {
        int r = i / 24;
        int q = i - r * 24;
        float4 v = make_float4(0.f, 0.f, 0.f, 0.f);
        if (row0 + r < n) v = ((const float4*)(X + (long)(row0 + r) * C))[q];
        *(float4*)(sX + r * SX_LD + q * 4) = v;
    }
    __syncthreads();

    const int tx = t & 15;   // 16 col-groups of 6
    const int ty = t >> 4;   // 16 row-groups of 4

    float acc[4][6];
#pragma unroll
    for (int r = 0; r < 4; r++)
#pragma unroll
        for (int c = 0; c < 6; c++) acc[r][c] = 0.f;

    const float* xbase = sX + (ty * 4) * SX_LD;
    const float* wbase = sW + tx * 6;

    for (int k = 0; k < C; k += 4) {
        float xv[4][4];
#pragma unroll
        for (int r = 0; r < 4; r++) {
            float4 v = *(const float4*)(xbase + r * SX_LD + k);
            xv[r][0] = v.x; xv[r][1] = v.y; xv[r][2] = v.z; xv[r][3] = v.w;
        }
#pragma unroll
        for (int dk = 0; dk < 4; dk++) {
            const float* wrow = wbase + (k + dk) * C;
#pragma unroll
            for (int c = 0; c < 6; c++) {
                float w = wrow[c];
#pragma unroll
                for (int r = 0; r < 4; r++) acc[r][c] += xv[r][dk] * w;
            }
        }
    }

    // Epilogue
#pragma unroll
    for (int r = 0; r < 4; r++) {
        int row = row0 + ty * 4 + r;
        if (row >= n) continue;
        float invd = FUSE ? INV[row] : 0.f;
#pragma unroll
        for (int c = 0; c < 6; c++) {
            int col = tx * 6 + c;
            float v = acc[r][c];
            if (FUSE) v = AGG[(long)row * C + col] * invd + v + BIAS[col];
            if (RELU) v = fmaxf(v, 0.f);
            Y[(long)row * C + col] = v;
        }
    }
}

// ---------------------------------------------------------------------------
extern "C" void kernel_launch(void* const* d_in, const int* in_sizes, int n_in,
                              void* d_out, int out_size, void* d_ws, size_t ws_size,
                              hipStream_t stream) {
    const float* x   = (const float*)d_in[0];
    const int*   ei  = (const int*)d_in[1];
    const float* W1  = (const float*)d_in[2];
    const float* Wr1 = (const float*)d_in[3];
    const float* b1  = (const float*)d_in[4];
    const float* W2  = (const float*)d_in[5];
    const float* Wr2 = (const float*)d_in[6];
    const float* b2  = (const float*)d_in[7];
    float* out = (float*)d_out;

    const int N = in_sizes[0] / C;      // 50000
    const int E = in_sizes[1] / 2;      // 800000
    const int* src = ei;
    const int* dst = ei + E;

    // Workspace layout (floats)
    float* deg = (float*)d_ws;            // N (padded to 50176)
    float* agg = deg + 50176;             // N*C
    float* h   = agg + (long)N * C;       // N*C (transform buffer, reused)
    float* h1  = h   + (long)N * C;       // N*C (layer-1 output)

    const int gemm_grid    = (N + TN - 1) / TN;
    const int scatter_grid = (E * 24 + 255) / 256;

    // zero deg + agg (contiguous)
    hipMemsetAsync(deg, 0, (size_t)(50176 + (long)N * C) * sizeof(float), stream);

    deg_kernel<<<(E + 255) / 256, 256, 0, stream>>>(dst, deg, E);
    inv_kernel<<<(N + 255) / 256, 256, 0, stream>>>(deg, N);

    // ---- Layer 1 ----
    gemm96_kernel<false, false><<<gemm_grid, 256, 0, stream>>>(x, W1, nullptr, nullptr, nullptr, h, N);
    scatter_kernel<<<scatter_grid, 256, 0, stream>>>(h, src, dst, agg, E);
    gemm96_kernel<true, true><<<gemm_grid, 256, 0, stream>>>(x, Wr1, agg, deg, b1, h1, N);

    // ---- Layer 2 ----
    hipMemsetAsync(agg, 0, (size_t)((long)N * C) * sizeof(float), stream);
    gemm96_kernel<false, false><<<gemm_grid, 256, 0, stream>>>(h1, W2, nullptr, nullptr, nullptr, h, N);
    scatter_kernel<<<scatter_grid, 256, 0, stream>>>(h, src, dst, agg, E);
    gemm96_kernel<true, false><<<gemm_grid, 256, 0, stream>>>(h1, Wr2, agg, deg, b2, out, N);
}

// Round 2
// 387.673 us; speedup vs baseline: 5.7481x; 5.7481x over previous
//
#include <hip/hip_runtime.h>

#define C 96
#define TN 64          // node rows per GEMM block
#define SX_LD 100      // padded LDS leading dim (breaks bank conflicts)
#define GNODES 16      // nodes per gather block (24 threads each -> 384 threads)

// ---------------------------------------------------------------------------
__global__ __launch_bounds__(256) void deg_count_kernel(const int* __restrict__ dst,
                                                        int* __restrict__ deg, int E) {
    int e = blockIdx.x * 256 + threadIdx.x;
    if (e < E) atomicAdd(&deg[dst[e]], 1);
}

// ---------------------------------------------------------------------------
// Prefix scan over deg -> row_off (exclusive). 1024 elems/block.
__global__ __launch_bounds__(256) void scan1_kernel(const int* __restrict__ deg,
                                                    int* __restrict__ row_off,
                                                    int* __restrict__ blocksum, int n) {
    __shared__ int s[256];
    int t = threadIdx.x;
    int base = blockIdx.x * 1024 + t * 4;
    int v[4], sum = 0;
#pragma unroll
    for (int i = 0; i < 4; i++) { v[i] = (base + i < n) ? deg[base + i] : 0; sum += v[i]; }
    s[t] = sum; __syncthreads();
    for (int off = 1; off < 256; off <<= 1) {
        int x = (t >= off) ? s[t - off] : 0;
        __syncthreads();
        s[t] += x;
        __syncthreads();
    }
    int run = s[t] - sum;   // exclusive prefix of this thread's chunk
#pragma unroll
    for (int i = 0; i < 4; i++) { if (base + i < n) row_off[base + i] = run; run += v[i]; }
    if (t == 255) blocksum[blockIdx.x] = s[255];
}

__global__ __launch_bounds__(256) void scan2_kernel(int* __restrict__ blocksum, int nb) {
    __shared__ int s[256];
    int t = threadIdx.x;
    int v = (t < nb) ? blocksum[t] : 0;
    s[t] = v; __syncthreads();
    for (int off = 1; off < 256; off <<= 1) {
        int x = (t >= off) ? s[t - off] : 0;
        __syncthreads();
        s[t] += x;
        __syncthreads();
    }
    if (t < nb) blocksum[t] = s[t] - v;  // exclusive
}

__global__ __launch_bounds__(256) void scan3_kernel(int* __restrict__ row_off,
                                                    int* __restrict__ cursor,
                                                    const int* __restrict__ blocksum, int n) {
    int i = blockIdx.x * 256 + threadIdx.x;
    if (i < n) {
        int v = row_off[i] + blocksum[i >> 10];
        row_off[i] = v;
        cursor[i] = v;
    }
}

// ---------------------------------------------------------------------------
__global__ __launch_bounds__(256) void fill_csr_kernel(const int* __restrict__ src,
                                                       const int* __restrict__ dst,
                                                       int* __restrict__ cursor,
                                                       int* __restrict__ csr, int E) {
    int e = blockIdx.x * 256 + threadIdx.x;
    if (e < E) {
        int p = atomicAdd(&cursor[dst[e]], 1);
        csr[p] = src[e];
    }
}

// ---------------------------------------------------------------------------
// Gather-mean: out[n] = (1/max(deg,1)) * sum_{s in neighbors(n)} X[s]
__global__ __launch_bounds__(24 * GNODES) void gather_mean_kernel(const float* __restrict__ X,
                                                                  const int* __restrict__ row_off,
                                                                  const int* __restrict__ deg,
                                                                  const int* __restrict__ csr,
                                                                  float* __restrict__ out, int n) {
    int t = threadIdx.x;
    int node = blockIdx.x * GNODES + t / 24;
    int q = t % 24;
    if (node >= n) return;
    int start = row_off[node];
    int d = deg[node];
    float4 acc = make_float4(0.f, 0.f, 0.f, 0.f);
    int j = 0;
    for (; j + 2 <= d; j += 2) {
        int s0 = csr[start + j];
        int s1 = csr[start + j + 1];
        float4 v0 = ((const float4*)(X + (long)s0 * C))[q];
        float4 v1 = ((const float4*)(X + (long)s1 * C))[q];
        acc.x += v0.x + v1.x; acc.y += v0.y + v1.y;
        acc.z += v0.z + v1.z; acc.w += v0.w + v1.w;
    }
    if (j < d) {
        int s0 = csr[start + j];
        float4 v0 = ((const float4*)(X + (long)s0 * C))[q];
        acc.x += v0.x; acc.y += v0.y; acc.z += v0.z; acc.w += v0.w;
    }
    float inv = 1.0f / fmaxf((float)d, 1.0f);
    ((float4*)(out + (long)node * C))[q] =
        make_float4(acc.x * inv, acc.y * inv, acc.z * inv, acc.w * inv);
}

// ---------------------------------------------------------------------------
// Dual GEMM: Y = (RELU?)(XA@WA + XB@WB + BIAS), all [n,96]x[96,96].
template <bool RELU>
__global__ __launch_bounds__(256) void gemm_dual_kernel(const float* __restrict__ XA,
                                                        const float* __restrict__ WA,
                                                        const float* __restrict__ XB,
                                                        const float* __restrict__ WB,
                                                        const float* __restrict__ BIAS,
                                                        float* __restrict__ Y, int n) {
    __shared__ float sW[C * C];
    __shared__ float sX[TN * SX_LD];

    const int t = threadIdx.x;
    const int row0 = blockIdx.x * TN;
    const int tx = t & 15;   // 16 col-groups of 6
    const int ty = t >> 4;   // 16 row-groups of 4

    float acc[4][6];
#pragma unroll
    for (int r = 0; r < 4; r++)
#pragma unroll
        for (int c = 0; c < 6; c++) acc[r][c] = 0.f;

    const float* Xs[2] = {XA, XB};
    const float* Ws[2] = {WA, WB};

    for (int ph = 0; ph < 2; ph++) {
        if (ph) __syncthreads();   // drain phase-0 reads before overwrite
        for (int i = t; i < C * C; i += 256) sW[i] = Ws[ph][i];
        for (int i = t; i < TN * 24; i += 256) {
            int r = i / 24, q = i - r * 24;
            float4 v = make_float4(0.f, 0.f, 0.f, 0.f);
            if (row0 + r < n) v = ((const float4*)(Xs[ph] + (long)(row0 + r) * C))[q];
            *(float4*)(sX + r * SX_LD + q * 4) = v;
        }
        __syncthreads();

        const float* xbase = sX + (ty * 4) * SX_LD;
        const float* wbase = sW + tx * 6;
        for (int k = 0; k < C; k += 4) {
            float xv[4][4];
#pragma unroll
            for (int r = 0; r < 4; r++) {
                float4 v = *(const float4*)(xbase + r * SX_LD + k);
                xv[r][0] = v.x; xv[r][1] = v.y; xv[r][2] = v.z; xv[r][3] = v.w;
            }
#pragma unroll
            for (int dk = 0; dk < 4; dk++) {
                const float* wrow = wbase + (k + dk) * C;
#pragma unroll
                for (int c = 0; c < 6; c++) {
                    float w = wrow[c];
#pragma unroll
                    for (int r = 0; r < 4; r++) acc[r][c] += xv[r][dk] * w;
                }
            }
        }
    }

#pragma unroll
    for (int r = 0; r < 4; r++) {
        int row = row0 + ty * 4 + r;
        if (row >= n) continue;
#pragma unroll
        for (int c = 0; c < 6; c++) {
            int col = tx * 6 + c;
            float v = acc[r][c] + BIAS[col];
            if (RELU) v = fmaxf(v, 0.f);
            Y[(long)row * C + col] = v;
        }
    }
}

// ---------------------------------------------------------------------------
extern "C" void kernel_launch(void* const* d_in, const int* in_sizes, int n_in,
                              void* d_out, int out_size, void* d_ws, size_t ws_size,
                              hipStream_t stream) {
    const float* x   = (const float*)d_in[0];
    const int*   ei  = (const int*)d_in[1];
    const float* W1  = (const float*)d_in[2];
    const float* Wr1 = (const float*)d_in[3];
    const float* b1  = (const float*)d_in[4];
    const float* W2  = (const float*)d_in[5];
    const float* Wr2 = (const float*)d_in[6];
    const float* b2  = (const float*)d_in[7];
    float* out = (float*)d_out;

    const int N = in_sizes[0] / C;      // 50000
    const int E = in_sizes[1] / 2;      // 800000
    const int* src = ei;
    const int* dst = ei + E;

    // Workspace layout (all 4-byte elems; float4 targets stay 16B-aligned)
    int Npad = (N + 63) & ~63;
    int Epad = (E + 63) & ~63;
    int*   deg      = (int*)d_ws;             // Npad
    int*   row_off  = deg + Npad;             // Npad
    int*   cursor   = row_off + Npad;         // Npad
    int*   blocksum = cursor + Npad;          // 256
    int*   csr      = blocksum + 256;         // Epad
    float* a        = (float*)(csr + Epad);   // N*C
    float* h1       = a + (size_t)N * C;      // N*C

    const int nb        = (N + 1023) / 1024;  // 49 (scan2 supports <=256)
    const int gemm_grid = (N + TN - 1) / TN;
    const int gath_grid = (N + GNODES - 1) / GNODES;

    hipMemsetAsync(deg, 0, (size_t)Npad * sizeof(int), stream);

    deg_count_kernel<<<(E + 255) / 256, 256, 0, stream>>>(dst, deg, E);
    scan1_kernel<<<nb, 256, 0, stream>>>(deg, row_off, blocksum, N);
    scan2_kernel<<<1, 256, 0, stream>>>(blocksum, nb);
    scan3_kernel<<<(N + 255) / 256, 256, 0, stream>>>(row_off, cursor, blocksum, N);
    fill_csr_kernel<<<(E + 255) / 256, 256, 0, stream>>>(src, dst, cursor, csr, E);

    // ---- Layer 1: h1 = relu(mean_agg(x)@W1 + x@Wr1 + b1) ----
    gather_mean_kernel<<<gath_grid, 24 * GNODES, 0, stream>>>(x, row_off, deg, csr, a, N);
    gemm_dual_kernel<true><<<gemm_grid, 256, 0, stream>>>(a, W1, x, Wr1, b1, h1, N);

    // ---- Layer 2: out = mean_agg(h1)@W2 + h1@Wr2 + b2 ----
    gather_mean_kernel<<<gath_grid, 24 * GNODES, 0, stream>>>(h1, row_off, deg, csr, a, N);
    gemm_dual_kernel<false><<<gemm_grid, 256, 0, stream>>>(a, W2, h1, Wr2, b2, out, N);
}

// Round 3
// 269.426 us; speedup vs baseline: 8.2709x; 1.4389x over previous
//
#include <hip/hip_runtime.h>

#define C 96
#define GN 16          // nodes per gather block (12 threads each -> 192 threads)
typedef unsigned short u16;
typedef unsigned int u32;
typedef __attribute__((ext_vector_type(8))) short short8;
typedef __attribute__((ext_vector_type(4))) float floatx4;

__device__ inline u16 f2bf(float f) {
    union { float f; u32 u; } v; v.f = f;
    u32 r = v.u + 0x7fff + ((v.u >> 16) & 1);   // RNE
    return (u16)(r >> 16);
}

// ---------------------------------------------------------------------------
__global__ __launch_bounds__(256) void deg_count_kernel(const int* __restrict__ dst,
                                                        int* __restrict__ deg, int E) {
    int e = blockIdx.x * 256 + threadIdx.x;
    if (e < E) atomicAdd(&deg[dst[e]], 1);
}

// Prefix scan over deg -> row_off (exclusive). 1024 elems/block.
__global__ __launch_bounds__(256) void scan1_kernel(const int* __restrict__ deg,
                                                    int* __restrict__ row_off,
                                                    int* __restrict__ blocksum, int n) {
    __shared__ int s[256];
    int t = threadIdx.x;
    int base = blockIdx.x * 1024 + t * 4;
    int v[4], sum = 0;
#pragma unroll
    for (int i = 0; i < 4; i++) { v[i] = (base + i < n) ? deg[base + i] : 0; sum += v[i]; }
    s[t] = sum; __syncthreads();
    for (int off = 1; off < 256; off <<= 1) {
        int x = (t >= off) ? s[t - off] : 0;
        __syncthreads();
        s[t] += x;
        __syncthreads();
    }
    int run = s[t] - sum;
#pragma unroll
    for (int i = 0; i < 4; i++) { if (base + i < n) row_off[base + i] = run; run += v[i]; }
    if (t == 255) blocksum[blockIdx.x] = s[255];
}

__global__ __launch_bounds__(256) void scan2_kernel(int* __restrict__ blocksum, int nb) {
    __shared__ int s[256];
    int t = threadIdx.x;
    int v = (t < nb) ? blocksum[t] : 0;
    s[t] = v; __syncthreads();
    for (int off = 1; off < 256; off <<= 1) {
        int x = (t >= off) ? s[t - off] : 0;
        __syncthreads();
        s[t] += x;
        __syncthreads();
    }
    if (t < nb) blocksum[t] = s[t] - v;
}

__global__ __launch_bounds__(256) void scan3_kernel(int* __restrict__ row_off,
                                                    int* __restrict__ cursor,
                                                    const int* __restrict__ blocksum, int n) {
    int i = blockIdx.x * 256 + threadIdx.x;
    if (i < n) {
        int v = row_off[i] + blocksum[i >> 10];
        row_off[i] = v;
        cursor[i] = v;
    }
}

__global__ __launch_bounds__(256) void fill_csr_kernel(const int* __restrict__ src,
                                                       const int* __restrict__ dst,
                                                       int* __restrict__ cursor,
                                                       int* __restrict__ csr, int E) {
    int e = blockIdx.x * 256 + threadIdx.x;
    if (e < E) {
        int p = atomicAdd(&cursor[dst[e]], 1);
        csr[p] = src[e];
    }
}

// ---------------------------------------------------------------------------
// x (fp32) -> xb (bf16), 8 elems/thread
__global__ __launch_bounds__(256) void convert_x_kernel(const float* __restrict__ x,
                                                        u16* __restrict__ xb, int n8) {
    int i = blockIdx.x * 256 + threadIdx.x;
    if (i >= n8) return;
    const float4* p = (const float4*)x + (size_t)i * 2;
    float4 a = p[0], b = p[1];
    short8 o;
    o[0] = (short)f2bf(a.x); o[1] = (short)f2bf(a.y);
    o[2] = (short)f2bf(a.z); o[3] = (short)f2bf(a.w);
    o[4] = (short)f2bf(b.x); o[5] = (short)f2bf(b.y);
    o[6] = (short)f2bf(b.z); o[7] = (short)f2bf(b.w);
    *(short8*)(xb + (size_t)i * 8) = o;
}

// W (fp32 [k][n]) -> WT (bf16 [n][k]), one matrix per block
__global__ __launch_bounds__(256) void convert_w_kernel(const float* W0, const float* W1,
                                                        const float* W2, const float* W3,
                                                        u16* T0, u16* T1, u16* T2, u16* T3) {
    const float* W = blockIdx.x == 0 ? W0 : blockIdx.x == 1 ? W1 : blockIdx.x == 2 ? W2 : W3;
    u16* T = blockIdx.x == 0 ? T0 : blockIdx.x == 1 ? T1 : blockIdx.x == 2 ? T2 : T3;
    for (int i = threadIdx.x; i < C * C; i += 256) {
        int k = i / C, n = i - k * C;
        T[n * C + k] = f2bf(W[i]);
    }
}

// ---------------------------------------------------------------------------
// Gather-mean over bf16: out[n] = bf16( (1/max(deg,1)) * sum X[neighbors] )
// 12 threads per node, 8 channels (16 B) each.
__global__ __launch_bounds__(12 * GN) void gather_kernel(const u16* __restrict__ X,
                                                         const int* __restrict__ row_off,
                                                         const int* __restrict__ deg,
                                                         const int* __restrict__ csr,
                                                         u16* __restrict__ out, int n) {
    int t = threadIdx.x;
    int node = blockIdx.x * GN + t / 12;
    int q = t - (t / 12) * 12;
    if (node >= n) return;
    int start = row_off[node];
    int d = deg[node];
    float acc[8];
#pragma unroll
    for (int i = 0; i < 8; i++) acc[i] = 0.f;
    int j = 0;
    for (; j + 2 <= d; j += 2) {
        int s0 = csr[start + j], s1 = csr[start + j + 1];
        uint4 v0 = *(const uint4*)(X + (size_t)s0 * C + q * 8);
        uint4 v1 = *(const uint4*)(X + (size_t)s1 * C + q * 8);
        u32 w0[4] = {v0.x, v0.y, v0.z, v0.w};
        u32 w1[4] = {v1.x, v1.y, v1.z, v1.w};
#pragma unroll
        for (int i = 0; i < 4; i++) {
            union { u32 u; float f; } a0, b0, a1, b1;
            a0.u = w0[i] << 16; b0.u = w0[i] & 0xffff0000u;
            a1.u = w1[i] << 16; b1.u = w1[i] & 0xffff0000u;
            acc[2 * i]     += a0.f + a1.f;
            acc[2 * i + 1] += b0.f + b1.f;
        }
    }
    if (j < d) {
        int s0 = csr[start + j];
        uint4 v0 = *(const uint4*)(X + (size_t)s0 * C + q * 8);
        u32 w0[4] = {v0.x, v0.y, v0.z, v0.w};
#pragma unroll
        for (int i = 0; i < 4; i++) {
            union { u32 u; float f; } a0, b0;
            a0.u = w0[i] << 16; b0.u = w0[i] & 0xffff0000u;
            acc[2 * i]     += a0.f;
            acc[2 * i + 1] += b0.f;
        }
    }
    float inv = 1.0f / fmaxf((float)d, 1.0f);
    short8 o;
#pragma unroll
    for (int i = 0; i < 8; i++) o[i] = (short)f2bf(acc[i] * inv);
    *(short8*)(out + (size_t)node * C + q * 8) = o;
}

// ---------------------------------------------------------------------------
// Dual MFMA GEMM: Y = (RELU?)(XA@WA + XB@WB + BIAS), A bf16 row-major [n,96],
// W given as bf16 transposed [96n][96k]. No LDS; 4 waves/block, 16 rows/wave.
// A-frag: A[m=lane&15][k=quad*8+j]; B-frag: B^T[n=lane&15][k=quad*8+j];
// C/D: col=lane&15, row=quad*4+reg.
template <bool RELU, typename OT>
__global__ __launch_bounds__(256) void gemm_dual_mfma(const u16* __restrict__ XA,
                                                      const u16* __restrict__ WTA,
                                                      const u16* __restrict__ XB,
                                                      const u16* __restrict__ WTB,
                                                      const float* __restrict__ BIAS,
                                                      OT* __restrict__ Y, int n) {
    const int lane = threadIdx.x & 63;
    const int w = threadIdx.x >> 6;
    const int quad = lane >> 4;
    const int l16 = lane & 15;
    const int row0 = blockIdx.x * 64 + w * 16;

    floatx4 acc[6];
#pragma unroll
    for (int i = 0; i < 6; i++) acc[i] = (floatx4){0.f, 0.f, 0.f, 0.f};

    int arow = row0 + l16;
    if (arow >= n) arow = n - 1;   // clamp loads; stores are guarded

    const u16* Xs[2] = {XA, XB};
    const u16* Ws[2] = {WTA, WTB};
#pragma unroll
    for (int ph = 0; ph < 2; ph++) {
        const u16* Xp = Xs[ph] + (size_t)arow * C + quad * 8;
        const u16* Wp = Ws[ph] + l16 * C + quad * 8;
#pragma unroll
        for (int ks = 0; ks < 3; ks++) {
            short8 a = *(const short8*)(Xp + ks * 32);
#pragma unroll
            for (int nt = 0; nt < 6; nt++) {
                short8 b = *(const short8*)(Wp + nt * 16 * C + ks * 32);
                acc[nt] = __builtin_amdgcn_mfma_f32_16x16x32_bf16(a, b, acc[nt], 0, 0, 0);
            }
        }
    }

#pragma unroll
    for (int nt = 0; nt < 6; nt++) {
        int cc = nt * 16 + l16;
        float bv = BIAS[cc];
#pragma unroll
        for (int r = 0; r < 4; r++) {
            int row = row0 + quad * 4 + r;
            if (row >= n) continue;
            float v = acc[nt][r] + bv;
            if (RELU) v = fmaxf(v, 0.f);
            if constexpr (sizeof(OT) == 2) Y[(size_t)row * C + cc] = (OT)f2bf(v);
            else                           Y[(size_t)row * C + cc] = (OT)v;
        }
    }
}

// ---------------------------------------------------------------------------
extern "C" void kernel_launch(void* const* d_in, const int* in_sizes, int n_in,
                              void* d_out, int out_size, void* d_ws, size_t ws_size,
                              hipStream_t stream) {
    const float* x   = (const float*)d_in[0];
    const int*   ei  = (const int*)d_in[1];
    const float* W1  = (const float*)d_in[2];
    const float* Wr1 = (const float*)d_in[3];
    const float* b1  = (const float*)d_in[4];
    const float* W2  = (const float*)d_in[5];
    const float* Wr2 = (const float*)d_in[6];
    const float* b2  = (const float*)d_in[7];
    float* out = (float*)d_out;

    const int N = in_sizes[0] / C;      // 50000
    const int E = in_sizes[1] / 2;      // 800000
    const int* src = ei;
    const int* dst = ei + E;

    // Workspace layout (16B-aligned sections)
    int Npad = (N + 63) & ~63;
    int Epad = (E + 63) & ~63;
    int*   deg      = (int*)d_ws;              // Npad
    int*   row_off  = deg + Npad;              // Npad
    int*   cursor   = row_off + Npad;          // Npad
    int*   blocksum = cursor + Npad;           // 256
    int*   csr      = blocksum + 256;          // Epad
    u16*   xb       = (u16*)(csr + Epad);      // N*C bf16
    u16*   ab       = xb + (size_t)N * C;      // N*C bf16 (gather output)
    u16*   h1b      = ab + (size_t)N * C;      // N*C bf16 (layer-1 output)
    u16*   wt       = h1b + (size_t)N * C;     // 4 * C*C bf16 (transposed weights)
    u16 *wt1 = wt, *wtr1 = wt + C * C, *wt2 = wt + 2 * C * C, *wtr2 = wt + 3 * C * C;

    const int nb        = (N + 1023) / 1024;
    const int gemm_grid = (N + 63) / 64;
    const int gath_grid = (N + GN - 1) / GN;
    const int n8        = N * C / 8;

    hipMemsetAsync(deg, 0, (size_t)Npad * sizeof(int), stream);

    deg_count_kernel<<<(E + 255) / 256, 256, 0, stream>>>(dst, deg, E);
    scan1_kernel<<<nb, 256, 0, stream>>>(deg, row_off, blocksum, N);
    scan2_kernel<<<1, 256, 0, stream>>>(blocksum, nb);
    scan3_kernel<<<(N + 255) / 256, 256, 0, stream>>>(row_off, cursor, blocksum, N);
    fill_csr_kernel<<<(E + 255) / 256, 256, 0, stream>>>(src, dst, cursor, csr, E);

    convert_x_kernel<<<(n8 + 255) / 256, 256, 0, stream>>>(x, xb, n8);
    convert_w_kernel<<<4, 256, 0, stream>>>(W1, Wr1, W2, Wr2, wt1, wtr1, wt2, wtr2);

    // ---- Layer 1: h1 = relu(mean_agg(x)@W1 + x@Wr1 + b1) ----
    gather_kernel<<<gath_grid, 12 * GN, 0, stream>>>(xb, row_off, deg, csr, ab, N);
    gemm_dual_mfma<true, u16><<<gemm_grid, 256, 0, stream>>>(ab, wt1, xb, wtr1, b1, h1b, N);

    // ---- Layer 2: out = mean_agg(h1)@W2 + h1@Wr2 + b2 ----
    gather_kernel<<<gath_grid, 12 * GN, 0, stream>>>(h1b, row_off, deg, csr, ab, N);
    gemm_dual_mfma<false, float><<<gemm_grid, 256, 0, stream>>>(ab, wt2, h1b, wtr2, b2, out, N);
}